// Round 3
// baseline (87.153 us; speedup 1.0000x reference)
//
#include <hip/hip_runtime.h>
#include <hip/hip_bf16.h>
#include <math.h>

// Dempster-Shafer evidential forward — fused single kernel (R8).
//   input [B,C,H,W,D] f32, W [K,C], BETA [K,M], alpha [K,1], gamma [K,1]
//   out   [B,M+1,H,W,D] f32;  K=20, C=16, M=4, B=2.
//
// Closed form: P_m = prod_k (1 - c_m[k]*e_k), O = prod_k (1 - a_k*e_k),
//   e_k = 2^(g2L*(x.W_k) - 0.5*g2L*||x||^2), constant 2^(-0.5*g2L*||W_k||^2)
//   folded into c_m[k]/a_k (R7, verified).
// Dot via v_mfma_f32_32x32x16_bf16: A=Wp[32 protos x 16 ch], B=X[16 ch x 32 elems];
// C/D col=lane&31=elem, row=(r&3)+8*(r>>2)+4*half=proto-row. ||x||^2 via second
// MFMA (a2=nh broadcast in K, b2=x_c^2). Protos 10+10 across halves, product
// loop uniform 10 iters, halves merged by shfl_xor(32). (R7, verified.)
//
// R8 changes vs R7 (theory: per-block serialization — x loads sat AFTER the
// prep barrier, so every block paid prep's global-latency chain before issuing
// its 4KB of x traffic; TSTEP=2 gave only 16 outstanding loads/lane):
//  - x prefetch issued BEFORE prep+barrier (loads depend only on ids) -> prep
//    latency hides under x-load latency.
//  - single-phase prep with inverse row->proto map, ONE barrier (was 2).
//  - TSTEP=4, grid=1024: 32 outstanding loads/lane, one block-round/CU.
#define NK 20
#define NC 16
#define NM 4
#define TSTEP 4

typedef __attribute__((ext_vector_type(8)))  short  short8;
typedef __attribute__((ext_vector_type(16))) float  floatx16;

static __device__ __forceinline__ short bf16b(float f) {
    __hip_bfloat16 h = __float2bfloat16(f);
    return *reinterpret_cast<short*>(&h);
}

__global__ __launch_bounds__(256, 4) void ds_fused(
    const float* __restrict__ inp,
    const float* __restrict__ Wg,
    const float* __restrict__ BETAg,
    const float* __restrict__ alphag,
    const float* __restrict__ gammag,
    float* __restrict__ out,
    int S,        // H*W*D = 262144
    int BS)       // B*S
{
    __shared__ __align__(16) float sCst[32][8];   // {c0,c1,c2,c3,aO,0,0,0} per C-row
    __shared__ __align__(16) short sWpb[32][16];  // bf16(g2L*W) by C-row, zero elsewhere
    __shared__ short sNh[32];                     // bf16(-0.5*g2L) per C-row

    const int t = threadIdx.x;
    const int lane = t & 63;
    const int half = lane >> 5;
    const int col  = lane & 31;
    const int gw   = blockIdx.x * 4 + (t >> 6);
    const int ebase = gw * (TSTEP * 32);          // wave's first element

    // ---- x prefetch FIRST (depends only on ids; issues before prep's loads).
    // Grid covers BS exactly; S % (TSTEP*32) == 0 so batch idx is wave-uniform.
    const int b   = (ebase >= S) ? 1 : 0;
    const int spw = ebase - b * S;
    const float* xb0 = inp + (size_t)b * NC * S + spw + col;
    float xv[TSTEP][8];
    #pragma unroll
    for (int tt = 0; tt < TSTEP; ++tt)
        #pragma unroll
        for (int j = 0; j < 8; ++j)
            xv[tt][j] = xb0[(size_t)(8*half + j) * S + tt*32];

    // ---- single-phase prep: row r <- proto tm+10*h where tm=(r&3)+4*(r>>3),
    // h=(r>>2)&1; live iff tm<10. Dead rows write zeros. One barrier.
    if (t < 32) {
        const int h   = (t >> 2) & 1;
        const int tm  = (t & 3) + 4 * (t >> 3);
        const bool live = (tm < 10);
        if (live) {
            const int k = tm + 10 * h;
            const float L   = 1.4426950408889634f;   // log2(e)
            const float g   = gammag[k];
            const float g2L = g * g * L;
            float w2 = 0.f;
            #pragma unroll
            for (int c = 0; c < NC; ++c) {
                const float w = Wg[k*NC + c];
                sWpb[t][c] = bf16b(g2L * w);
                w2 = fmaf(w, w, w2);
            }
            const float nh = -0.5f * g2L;
            sNh[t] = bf16b(nh);
            const float p2nbk = exp2f(nh * w2);             // 2^(-0.5*g2L*||W||^2)
            const float a  = 0.99f / (1.0f + __expf(-alphag[k]));
            const float ap = a * p2nbk;
            float b0 = BETAg[k*NM+0], b1 = BETAg[k*NM+1], b2 = BETAg[k*NM+2], b3 = BETAg[k*NM+3];
            b0 *= b0; b1 *= b1; b2 *= b2; b3 *= b3;
            const float uinv = 1.0f / (b0 + b1 + b2 + b3);
            sCst[t][0] = (1.0f - b0*uinv) * ap;
            sCst[t][1] = (1.0f - b1*uinv) * ap;
            sCst[t][2] = (1.0f - b2*uinv) * ap;
            sCst[t][3] = (1.0f - b3*uinv) * ap;
            sCst[t][4] = ap;
            sCst[t][5] = 0.f; sCst[t][6] = 0.f; sCst[t][7] = 0.f;
        } else {
            #pragma unroll
            for (int i = 0; i < 8; ++i) sCst[t][i] = 0.f;
            #pragma unroll
            for (int c = 0; c < NC; ++c) sWpb[t][c] = 0;
            sNh[t] = 0;
        }
    }
    __syncthreads();

    // ---- wave-invariant fragments
    const short8 afrag = *(const short8*)&sWpb[col][half*8];
    const short  nhb   = sNh[col];
    short8 nhfrag;
    #pragma unroll
    for (int j = 0; j < 8; ++j) nhfrag[j] = nhb;

    #pragma unroll
    for (int tt = 0; tt < TSTEP; ++tt) {
        const int sp = spw + tt*32 + col;

        short8 bfrag, b2frag;
        #pragma unroll
        for (int j = 0; j < 8; ++j) {
            const float v = xv[tt][j];
            bfrag[j]  = bf16b(v);
            b2frag[j] = bf16b(v * v);
        }

        floatx16 acc;
        #pragma unroll
        for (int i = 0; i < 16; ++i) acc[i] = 0.f;
        acc = __builtin_amdgcn_mfma_f32_32x32x16_bf16(afrag,  bfrag,  acc, 0, 0, 0);
        acc = __builtin_amdgcn_mfma_f32_32x32x16_bf16(nhfrag, b2frag, acc, 0, 0, 0);

        float P0 = 1.f, P1 = 1.f, P2 = 1.f, P3 = 1.f, PO = 1.f;
        #pragma unroll
        for (int r = 0; r < 10; ++r) {
            const int p = (r & 3) + 8*(r >> 2) + 4*half;     // live C-row for this half
            const float4 cv = *(const float4*)&sCst[p][0];   // LDS broadcast
            const float  aO = sCst[p][4];
            const float  ek = __builtin_amdgcn_exp2f(acc[r]);
            P0 *= fmaf(-cv.x, ek, 1.0f);
            P1 *= fmaf(-cv.y, ek, 1.0f);
            P2 *= fmaf(-cv.z, ek, 1.0f);
            P3 *= fmaf(-cv.w, ek, 1.0f);
            PO *= fmaf(-aO,   ek, 1.0f);
        }
        // merge the halves' disjoint proto subsets
        P0 *= __shfl_xor(P0, 32, 64);
        P1 *= __shfl_xor(P1, 32, 64);
        P2 *= __shfl_xor(P2, 32, 64);
        P3 *= __shfl_xor(P3, 32, 64);
        PO *= __shfl_xor(PO, 32, 64);

        const float O  = PO;
        const float f0 = P0 - O, f1 = P1 - O, f2 = P2 - O, f3 = P3 - O;
        const float inv = 1.0f / (f0 + f1 + f2 + f3 + O);

        float* op = out + (size_t)b * (NM+1) * S + sp;
        if (half == 0) {
            op[0]           = f0 * inv;
            op[(size_t)S]   = f1 * inv;
            op[(size_t)2*S] = f2 * inv;
        } else {
            op[(size_t)3*S] = f3 * inv;
            op[(size_t)4*S] = O  * inv;
        }
    }
}

extern "C" void kernel_launch(void* const* d_in, const int* in_sizes, int n_in,
                              void* d_out, int out_size, void* d_ws, size_t ws_size,
                              hipStream_t stream) {
    const float* inp   = (const float*)d_in[0];
    const float* Wg    = (const float*)d_in[1];
    const float* BETAg = (const float*)d_in[2];
    const float* alphag= (const float*)d_in[3];
    const float* gammag= (const float*)d_in[4];
    float* out = (float*)d_out;

    const int BS = in_sizes[0] / NC;   // B*S = 524288
    const int S  = BS / 2;             // 262144 (B=2 fixed by setup_inputs)

    // one wave covers TSTEP*32 = 128 elems; 4 waves/block -> 512 elems/block
    const int elems_per_block = 4 * TSTEP * 32;
    const int grid = (BS + elems_per_block - 1) / elems_per_block;  // 1024, exact
    ds_fused<<<grid, 256, 0, stream>>>(inp, Wg, BETAg, alphag, gammag, out, S, BS);
}